// Round 5
// baseline (538.395 us; speedup 1.0000x reference)
//
#include <hip/hip_runtime.h>
#include <hip/hip_bf16.h>
#include <float.h>

// Problem: B=128, D=64, H=W=32, K=512. N = 131072 rows.
#define NTOT 131072

// d_out element offsets (fp32, concatenated in return order)
#define OFF_LOSS  0
#define OFF_QUANT 1
#define OFF_PERP  8388609
#define OFF_OH    8388610

#define FLAG_BIT (1 << 16)
#define TAU      1.5e-3f
#define MAGIC    0x5EEDF00D
#define WSTRIDE  516          // per-WG ints in ws: 512 hist + loss + flag + pad

typedef __attribute__((ext_vector_type(8))) short short8;
typedef __attribute__((ext_vector_type(4))) short short4v;
typedef __attribute__((ext_vector_type(4))) float f32x4;

__device__ inline unsigned short f2bf(float f) {
    unsigned u = __builtin_bit_cast(unsigned, f);
    unsigned r = (u + 0x7fffu + ((u >> 16) & 1u)) >> 16;   // RNE
    return (unsigned short)r;
}
__device__ inline float bf2f(unsigned short h) {
    return __builtin_bit_cast(float, ((unsigned)h) << 16);
}

// ONE persistent kernel, 256 WG x 1024 thr (1 WG/CU). ONE wg-wide barrier
// (after LDS staging); everything after is wave-local: each wave owns 32 rows
// (merge -> recheck -> hist -> its own output slices). Last-arriving wave
// publishes WG stats (LDS arrival counter); WG0 gathers at the very end.
__global__ __launch_bounds__(1024)
void vq_fused(const float* __restrict__ x, const float* __restrict__ cb,
              int* __restrict__ wsi, float* __restrict__ out) {
    __shared__ short Ehi[512 * 64];   // bf16 hi, XOR-swizzled 16B chunks
    __shared__ short Elo[512 * 64];   // bf16 lo
    __shared__ float en_s[512];
    __shared__ float dist_s[512];
    __shared__ int   idx_s[512];
    __shared__ int   hist_s[512];
    __shared__ float loss_s;
    __shared__ int   cnt_s;

    const int t = threadIdx.x, wg = blockIdx.x;
    const int w = t >> 6, lane = t & 63;
    const int c = lane & 15, g = lane >> 4;
    const int b0 = wg >> 1;
    const int sphalf = (wg & 1) << 9;
    float* qout = out + OFF_QUANT;
    float* oh   = out + OFF_OH;

    if (t < 512) hist_s[t] = 0;
    if (t == 0) { loss_s = 0.f; cnt_s = 0; }

    // ---- stage codebook -> LDS bf16 hi/lo, swizzle: 16B chunk' = chunk ^ (k&7) ----
    const float4* cb4 = (const float4*)cb;
#pragma unroll
    for (int i = 0; i < 8; ++i) {
        int e4 = i * 1024 + t;                 // 8192 float4 = full codebook
        float4 v = cb4[e4];
        int k = e4 >> 4, q = e4 & 15;
        int base = (k << 6) + ((((q >> 1) ^ (k & 7)) << 3) + ((q & 1) << 2));
        float vv[4] = {v.x, v.y, v.z, v.w};
        short4v h4, l4;
#pragma unroll
        for (int e = 0; e < 4; ++e) {
            unsigned short h = f2bf(vv[e]);
            h4[e] = (short)h;
            l4[e] = (short)f2bf(vv[e] - bf2f(h));
        }
        *(short4v*)&Ehi[base] = h4;
        *(short4v*)&Elo[base] = l4;
    }
    // ---- ||e||^2 fp32 ----
    if (t < 512) {
        const float4* r4 = cb4 + (t << 4);
        float s = 0.f;
#pragma unroll
        for (int j = 0; j < 16; ++j) {
            float4 vv = r4[j];
            s = fmaf(vv.x, vv.x, s); s = fmaf(vv.y, vv.y, s);
            s = fmaf(vv.z, vv.z, s); s = fmaf(vv.w, vv.w, s);
        }
        en_s[t] = s;
    }

    // ---- X B-frags + xnorm, registers only ----
    short8 bh[2][2], bl[2][2];
    float xn2[2] = {0.f, 0.f};
    const float* xb = x + (((size_t)b0) << 16) + sphalf + (w << 5) + c;
#pragma unroll
    for (int xt = 0; xt < 2; ++xt) {
#pragma unroll
        for (int ks = 0; ks < 2; ++ks) {
            short8 h8, l8;
#pragma unroll
            for (int e = 0; e < 8; ++e) {
                float xv = xb[(xt << 4) + ((size_t)((ks << 5) + (g << 3) + e) << 10)];
                unsigned short hh = f2bf(xv);
                h8[e] = (short)hh;
                l8[e] = (short)f2bf(xv - bf2f(hh));
                xn2[xt] = fmaf(xv, xv, xn2[xt]);
            }
            bh[xt][ks] = h8; bl[xt][ks] = l8;
        }
    }
    float xnorm[2];
#pragma unroll
    for (int xt = 0; xt < 2; ++xt) {
        float v = xn2[xt];
        v += __shfl_xor(v, 16);
        v += __shfl_xor(v, 32);
        xnorm[xt] = v;
    }
    __syncthreads();      // the ONLY WG-wide barrier

    // ---- MFMA argmin over 32 k-tiles ----
    float v1[2] = {FLT_MAX, FLT_MAX}, v2[2] = {FLT_MAX, FLT_MAX};
    int   i1[2] = {0, 0},            i2v[2] = {0, 0};
    const int sw = c & 7;
    const short* ph = &Ehi[c << 6];
    const short* pl = &Elo[c << 6];
#pragma unroll 2
    for (int kt = 0; kt < 32; ++kt) {
        const short* rh = ph + (kt << 10);
        const short* rl = pl + (kt << 10);
        short8 ah0 = *(const short8*)(rh + ((g ^ sw) << 3));
        short8 ah1 = *(const short8*)(rh + (((g + 4) ^ sw) << 3));
        short8 al0 = *(const short8*)(rl + ((g ^ sw) << 3));
        short8 al1 = *(const short8*)(rl + (((g + 4) ^ sw) << 3));
        float4 en4 = *(const float4*)&en_s[(kt << 4) + (g << 2)];
        float en_[4] = {en4.x, en4.y, en4.z, en4.w};
#pragma unroll
        for (int xt = 0; xt < 2; ++xt) {
            f32x4 acc = {0.f, 0.f, 0.f, 0.f};
            acc = __builtin_amdgcn_mfma_f32_16x16x32_bf16(ah0, bh[xt][0], acc, 0, 0, 0);
            acc = __builtin_amdgcn_mfma_f32_16x16x32_bf16(ah1, bh[xt][1], acc, 0, 0, 0);
            acc = __builtin_amdgcn_mfma_f32_16x16x32_bf16(al0, bh[xt][0], acc, 0, 0, 0);
            acc = __builtin_amdgcn_mfma_f32_16x16x32_bf16(al1, bh[xt][1], acc, 0, 0, 0);
            acc = __builtin_amdgcn_mfma_f32_16x16x32_bf16(ah0, bl[xt][0], acc, 0, 0, 0);
            acc = __builtin_amdgcn_mfma_f32_16x16x32_bf16(ah1, bl[xt][1], acc, 0, 0, 0);
#pragma unroll
            for (int r = 0; r < 4; ++r) {
                float dd = fmaf(-2.0f, acc[r], en_[r]);
                int k = (kt << 4) + (g << 2) + r;
                bool lt1 = dd < v1[xt];
                bool lt2 = dd < v2[xt];
                v2[xt] = lt1 ? v1[xt] : (lt2 ? dd : v2[xt]);
                i2v[xt] = lt1 ? i1[xt] : (lt2 ? k : i2v[xt]);
                v1[xt] = lt1 ? dd : v1[xt];
                i1[xt] = lt1 ? k : i1[xt];
            }
        }
    }

    // ---- cross-lane merge (wave-local) ----
#pragma unroll
    for (int xt = 0; xt < 2; ++xt) {
        float V1 = v1[xt], V2 = v2[xt]; int I1 = i1[xt], I2 = i2v[xt];
#pragma unroll
        for (int off = 16; off <= 32; off <<= 1) {
            float o1 = __shfl_xor(V1, off); int oi1 = __shfl_xor(I1, off);
            float o2 = __shfl_xor(V2, off); int oi2 = __shfl_xor(I2, off);
            if (o1 < V1 || (o1 == V1 && oi1 < I1)) {
                V2 = V1; I2 = I1; V1 = o1; I1 = oi1;
            } else if (o1 < V2 || (o1 == V2 && oi1 < I2)) { V2 = o1; I2 = oi1; }
            if (o2 < V2 || (o2 == V2 && oi2 < I2)) { V2 = o2; I2 = oi2; }
        }
        if (g == 0) {
            int r = (w << 5) + (xt << 4) + c;
            idx_s[r]  = I1 | ((V2 - V1 < TAU) ? FLAG_BIT : 0);
            dist_s[r] = xnorm[xt] + V1;
        }
    }

    // ---- wave-local fp64 recheck of near-ties (float4-gathered cb) ----
    {
        int rowfull = (lane < 32) ? idx_s[(w << 5) + lane] : 0;
        unsigned long long m = __ballot((lane < 32) && (rowfull & FLAG_BIT));
        while (m) {
            int r = __ffsll((long long)m) - 1; m &= m - 1;
            int sp = sphalf + (w << 5) + r;
            float xd = x[(((size_t)b0) << 16) + (((size_t)lane) << 10) + sp]; // lane = d
            double bestd = 1e300; int besti = 0x7fffffff;
            for (int kk = 0; kk < 8; ++kk) {
                int k = (lane << 3) + kk;
                double s = 0.0;
#pragma unroll
                for (int d4 = 0; d4 < 16; ++d4) {
                    float4 e4 = cb4[(k << 4) + d4];
                    float x0 = __shfl(xd, d4 * 4 + 0);
                    float x1 = __shfl(xd, d4 * 4 + 1);
                    float x2 = __shfl(xd, d4 * 4 + 2);
                    float x3 = __shfl(xd, d4 * 4 + 3);
                    double f0 = (double)x0 - (double)e4.x; s = fma(f0, f0, s);
                    double f1 = (double)x1 - (double)e4.y; s = fma(f1, f1, s);
                    double f2 = (double)x2 - (double)e4.z; s = fma(f2, f2, s);
                    double f3 = (double)x3 - (double)e4.w; s = fma(f3, f3, s);
                }
                if (s < bestd || (s == bestd && k < besti)) { bestd = s; besti = k; }
            }
#pragma unroll
            for (int off = 32; off; off >>= 1) {
                double od = __shfl_xor(bestd, off);
                int    oi = __shfl_xor(besti, off);
                if (od < bestd || (od == bestd && oi < besti)) { bestd = od; besti = oi; }
            }
            if (lane == 0) {
                idx_s[(w << 5) + r]  = besti;           // flag stripped
                dist_s[(w << 5) + r] = (float)bestd;
            }
        }
    }

    // ---- wave-local stats: strip flags, LDS hist, loss partial ----
    if (lane < 32) {
        int r = (w << 5) + lane;
        int k = idx_s[r] & 511;
        idx_s[r] = k;
        atomicAdd(&hist_s[k], 1);
    }
    {
        float lv = (lane < 32) ? dist_s[(w << 5) + lane] : 0.f;
#pragma unroll
        for (int off = 1; off < 64; off <<= 1) lv += __shfl_xor(lv, off);
        if (lane == 0) atomicAdd(&loss_s, lv);
    }
    __threadfence_block();
    int old16 = 0;
    if (lane == 0) old16 = atomicAdd(&cnt_s, 1);
    old16 = __shfl(old16, 0);
    if (old16 == 15) {
        // last wave publishes this WG's stats slice
#pragma unroll
        for (int j = 0; j < 8; ++j)
            __hip_atomic_store(&wsi[wg * WSTRIDE + lane + (j << 6)],
                               hist_s[lane + (j << 6)],
                               __ATOMIC_RELAXED, __HIP_MEMORY_SCOPE_AGENT);
        if (lane == 0)
            __hip_atomic_store(&wsi[wg * WSTRIDE + 512], __float_as_int(loss_s),
                               __ATOMIC_RELAXED, __HIP_MEMORY_SCOPE_AGENT);
        __threadfence();
        if (lane == 0)
            __hip_atomic_store(&wsi[wg * WSTRIDE + 513], MAGIC,
                               __ATOMIC_RELEASE, __HIP_MEMORY_SCOPE_AGENT);
    }

    // ---- onehot slice (wave-local rows; float2 -> 128B segments per 16 lanes) ----
    {
        const int pr = lane & 15, kk = lane >> 4;
        int2 iv = *(const int2*)&idx_s[(w << 5) + (pr << 1)];
        float* p = oh + (((size_t)b0) << 19) + sphalf + (w << 5) + (pr << 1)
                     + (((size_t)kk) << 10);
#pragma unroll 8
        for (int kb = 0; kb < 512; kb += 4) {
            int k = kb + kk;
            float2 o;
            o.x = (iv.x == k) ? 1.f : 0.f;
            o.y = (iv.y == k) ? 1.f : 0.f;
            *(float2*)p = o;
            p += 4096;
        }
    }
    // ---- quantized slice (reconstruct hi+lo from LDS) ----
    {
        const int sp_l = lane & 31, dg = lane >> 5;
        int k = idx_s[(w << 5) + sp_l];
        const short* phq = &Ehi[k << 6];
        const short* plq = &Elo[k << 6];
        const int swq = k & 7;
        float* qb = qout + (((size_t)b0) << 16) + sphalf + (w << 5) + sp_l;
#pragma unroll
        for (int dblk = 0; dblk < 4; ++dblk) {
            int chunk = (dg << 2) + dblk;
            short8 h8 = *(const short8*)(phq + ((chunk ^ swq) << 3));
            short8 l8 = *(const short8*)(plq + ((chunk ^ swq) << 3));
#pragma unroll
            for (int e = 0; e < 8; ++e) {
                float v = bf2f((unsigned short)h8[e]) + bf2f((unsigned short)l8[e]);
                qb[((size_t)((dg << 5) + (dblk << 3) + e)) << 10] = v;
            }
        }
    }

    // ---- WG0: gather all stats, perplexity + loss ----
    if (wg == 0) {
        if (t < 256) {
            while (__hip_atomic_load(&wsi[t * WSTRIDE + 513],
                                     __ATOMIC_ACQUIRE, __HIP_MEMORY_SCOPE_AGENT) != MAGIC)
                __builtin_amdgcn_s_sleep(2);
        }
        __syncthreads();
        float plog = 0.f, lpart = 0.f;
        if (t < 512) {
            int s = 0;
            for (int wgi = 0; wgi < 256; ++wgi)
                s += __hip_atomic_load(&wsi[wgi * WSTRIDE + t],
                                       __ATOMIC_RELAXED, __HIP_MEMORY_SCOPE_AGENT);
            float p = (float)s * (1.f / (float)NTOT);
            plog = p * logf(p + 1e-10f);
        }
        if (t < 256)
            lpart = __int_as_float(__hip_atomic_load(&wsi[t * WSTRIDE + 512],
                                       __ATOMIC_RELAXED, __HIP_MEMORY_SCOPE_AGENT));
#pragma unroll
        for (int off = 1; off < 64; off <<= 1) {
            plog  += __shfl_xor(plog, off);
            lpart += __shfl_xor(lpart, off);
        }
        __syncthreads();
        if (lane == 0 && w < 8) en_s[w] = plog;
        if (lane == 0 && w < 4) dist_s[w] = lpart;
        __syncthreads();
        if (t == 0) {
            float ps = 0.f; for (int i = 0; i < 8; ++i) ps += en_s[i];
            float ls = 0.f; for (int i = 0; i < 4; ++i) ls += dist_s[i];
            out[OFF_PERP] = expf(-ps);
            out[OFF_LOSS] = 0.25f * ls / ((float)NTOT * 64.0f);
        }
    }
}

extern "C" void kernel_launch(void* const* d_in, const int* in_sizes, int n_in,
                              void* d_out, int out_size, void* d_ws, size_t ws_size,
                              hipStream_t stream) {
    const float* x  = (const float*)d_in[0];
    const float* cb = (const float*)d_in[1];
    vq_fused<<<256, 1024, 0, stream>>>(x, cb, (int*)d_ws, (float*)d_out);
}

// Round 6
// 417.644 us; speedup vs baseline: 1.2891x; 1.2891x over previous
//
#include <hip/hip_runtime.h>
#include <hip/hip_bf16.h>
#include <float.h>

// Problem: B=128, D=64, H=W=32, K=512. N = 131072 rows.
#define NTOT 131072

// d_out element offsets (fp32, concatenated in return order)
#define OFF_LOSS  0
#define OFF_QUANT 1
#define OFF_PERP  8388609
#define OFF_OH    8388610

#define FLAG_BIT (1 << 16)
#define TAU      1.5e-3f
#define MAGIC    0x5EEDF00D
#define WSTRIDE  516          // per-WG ints in ws: 512 hist + loss + flag + pad

typedef __attribute__((ext_vector_type(8))) short short8;
typedef __attribute__((ext_vector_type(4))) short short4v;
typedef __attribute__((ext_vector_type(4))) float f32x4;

__device__ inline unsigned short f2bf(float f) {
    unsigned u = __builtin_bit_cast(unsigned, f);
    unsigned r = (u + 0x7fffu + ((u >> 16) & 1u)) >> 16;   // RNE
    return (unsigned short)r;
}
__device__ inline float bf2f(unsigned short h) {
    return __builtin_bit_cast(float, ((unsigned)h) << 16);
}

// ONE persistent kernel, 256 WG x 1024 thr (1 WG/CU). Round-4 barrier
// skeleton (measured best: convoyed phases). Store phases reworked:
// onehot = wide zero-fill + 512-dword scatter; quant = float4 with edge
// handling for the odd base alignment.
__global__ __launch_bounds__(1024)
void vq_fused(const float* __restrict__ x, const float* __restrict__ cb,
              int* __restrict__ wsi, float* __restrict__ out) {
    __shared__ short Ehi[512 * 64];   // bf16 hi, XOR-swizzled 16B chunks
    __shared__ short Elo[512 * 64];   // bf16 lo
    __shared__ float en_s[512];
    __shared__ float dist_s[512];
    __shared__ int   idx_s[512];
    __shared__ int   hist_s[512];

    const int t = threadIdx.x, wg = blockIdx.x;
    const int w = t >> 6, lane = t & 63;
    const int c = lane & 15, g = lane >> 4;
    const int b0 = wg >> 1;
    const int sphalf = (wg & 1) << 9;
    float* qout = out + OFF_QUANT;
    float* oh   = out + OFF_OH;

    if (t < 512) hist_s[t] = 0;

    // ---- stage codebook -> LDS bf16 hi/lo, swizzle: 16B chunk' = chunk ^ (k&7) ----
    const float4* cb4 = (const float4*)cb;
#pragma unroll
    for (int i = 0; i < 8; ++i) {
        int e4 = i * 1024 + t;                 // 8192 float4 = full codebook
        float4 v = cb4[e4];
        int k = e4 >> 4, q = e4 & 15;
        int base = (k << 6) + ((((q >> 1) ^ (k & 7)) << 3) + ((q & 1) << 2));
        float vv[4] = {v.x, v.y, v.z, v.w};
        short4v h4, l4;
#pragma unroll
        for (int e = 0; e < 4; ++e) {
            unsigned short h = f2bf(vv[e]);
            h4[e] = (short)h;
            l4[e] = (short)f2bf(vv[e] - bf2f(h));
        }
        *(short4v*)&Ehi[base] = h4;
        *(short4v*)&Elo[base] = l4;
    }
    // ---- ||e||^2 fp32 ----
    if (t < 512) {
        const float4* r4 = cb4 + (t << 4);
        float s = 0.f;
#pragma unroll
        for (int j = 0; j < 16; ++j) {
            float4 vv = r4[j];
            s = fmaf(vv.x, vv.x, s); s = fmaf(vv.y, vv.y, s);
            s = fmaf(vv.z, vv.z, s); s = fmaf(vv.w, vv.w, s);
        }
        en_s[t] = s;
    }

    // ---- X B-frags + xnorm, registers only ----
    short8 bh[2][2], bl[2][2];
    float xn2[2] = {0.f, 0.f};
    const float* xb = x + (((size_t)b0) << 16) + sphalf + (w << 5) + c;
#pragma unroll
    for (int xt = 0; xt < 2; ++xt) {
#pragma unroll
        for (int ks = 0; ks < 2; ++ks) {
            short8 h8, l8;
#pragma unroll
            for (int e = 0; e < 8; ++e) {
                float xv = xb[(xt << 4) + ((size_t)((ks << 5) + (g << 3) + e) << 10)];
                unsigned short hh = f2bf(xv);
                h8[e] = (short)hh;
                l8[e] = (short)f2bf(xv - bf2f(hh));
                xn2[xt] = fmaf(xv, xv, xn2[xt]);
            }
            bh[xt][ks] = h8; bl[xt][ks] = l8;
        }
    }
    float xnorm[2];
#pragma unroll
    for (int xt = 0; xt < 2; ++xt) {
        float v = xn2[xt];
        v += __shfl_xor(v, 16);
        v += __shfl_xor(v, 32);
        xnorm[xt] = v;
    }
    __syncthreads();

    // ---- MFMA argmin over 32 k-tiles ----
    float v1[2] = {FLT_MAX, FLT_MAX}, v2[2] = {FLT_MAX, FLT_MAX};
    int   i1[2] = {0, 0},            i2v[2] = {0, 0};
    const int sw = c & 7;
    const short* ph = &Ehi[c << 6];
    const short* pl = &Elo[c << 6];
#pragma unroll 2
    for (int kt = 0; kt < 32; ++kt) {
        const short* rh = ph + (kt << 10);
        const short* rl = pl + (kt << 10);
        short8 ah0 = *(const short8*)(rh + ((g ^ sw) << 3));
        short8 ah1 = *(const short8*)(rh + (((g + 4) ^ sw) << 3));
        short8 al0 = *(const short8*)(rl + ((g ^ sw) << 3));
        short8 al1 = *(const short8*)(rl + (((g + 4) ^ sw) << 3));
        float4 en4 = *(const float4*)&en_s[(kt << 4) + (g << 2)];
        float en_[4] = {en4.x, en4.y, en4.z, en4.w};
#pragma unroll
        for (int xt = 0; xt < 2; ++xt) {
            f32x4 acc = {0.f, 0.f, 0.f, 0.f};
            acc = __builtin_amdgcn_mfma_f32_16x16x32_bf16(ah0, bh[xt][0], acc, 0, 0, 0);
            acc = __builtin_amdgcn_mfma_f32_16x16x32_bf16(ah1, bh[xt][1], acc, 0, 0, 0);
            acc = __builtin_amdgcn_mfma_f32_16x16x32_bf16(al0, bh[xt][0], acc, 0, 0, 0);
            acc = __builtin_amdgcn_mfma_f32_16x16x32_bf16(al1, bh[xt][1], acc, 0, 0, 0);
            acc = __builtin_amdgcn_mfma_f32_16x16x32_bf16(ah0, bl[xt][0], acc, 0, 0, 0);
            acc = __builtin_amdgcn_mfma_f32_16x16x32_bf16(ah1, bl[xt][1], acc, 0, 0, 0);
#pragma unroll
            for (int r = 0; r < 4; ++r) {
                float dd = fmaf(-2.0f, acc[r], en_[r]);
                int k = (kt << 4) + (g << 2) + r;
                bool lt1 = dd < v1[xt];
                bool lt2 = dd < v2[xt];
                v2[xt] = lt1 ? v1[xt] : (lt2 ? dd : v2[xt]);
                i2v[xt] = lt1 ? i1[xt] : (lt2 ? k : i2v[xt]);
                v1[xt] = lt1 ? dd : v1[xt];
                i1[xt] = lt1 ? k : i1[xt];
            }
        }
    }

    // ---- cross-lane merge ----
#pragma unroll
    for (int xt = 0; xt < 2; ++xt) {
        float V1 = v1[xt], V2 = v2[xt]; int I1 = i1[xt], I2 = i2v[xt];
#pragma unroll
        for (int off = 16; off <= 32; off <<= 1) {
            float o1 = __shfl_xor(V1, off); int oi1 = __shfl_xor(I1, off);
            float o2 = __shfl_xor(V2, off); int oi2 = __shfl_xor(I2, off);
            if (o1 < V1 || (o1 == V1 && oi1 < I1)) {
                V2 = V1; I2 = I1; V1 = o1; I1 = oi1;
            } else if (o1 < V2 || (o1 == V2 && oi1 < I2)) { V2 = o1; I2 = oi1; }
            if (o2 < V2 || (o2 == V2 && oi2 < I2)) { V2 = o2; I2 = oi2; }
        }
        if (g == 0) {
            int r = (w << 5) + (xt << 4) + c;
            idx_s[r]  = I1 | ((V2 - V1 < TAU) ? FLAG_BIT : 0);
            dist_s[r] = xnorm[xt] + V1;
        }
    }
    __syncthreads();

    // ---- wave-local fp64 recheck of near-ties ----
    {
        int rowfull = (lane < 32) ? idx_s[(w << 5) + lane] : 0;
        unsigned long long m = __ballot((lane < 32) && (rowfull & FLAG_BIT));
        while (m) {
            int r = __ffsll((long long)m) - 1; m &= m - 1;
            int sp = sphalf + (w << 5) + r;
            float xd = x[(((size_t)b0) << 16) + (((size_t)lane) << 10) + sp]; // lane = d
            double bestd = 1e300; int besti = 0x7fffffff;
            for (int kk = 0; kk < 8; ++kk) {
                int k = (lane << 3) + kk;
                double s = 0.0;
#pragma unroll
                for (int d4 = 0; d4 < 16; ++d4) {
                    float4 e4 = cb4[(k << 4) + d4];
                    float x0 = __shfl(xd, d4 * 4 + 0);
                    float x1 = __shfl(xd, d4 * 4 + 1);
                    float x2 = __shfl(xd, d4 * 4 + 2);
                    float x3 = __shfl(xd, d4 * 4 + 3);
                    double f0 = (double)x0 - (double)e4.x; s = fma(f0, f0, s);
                    double f1 = (double)x1 - (double)e4.y; s = fma(f1, f1, s);
                    double f2 = (double)x2 - (double)e4.z; s = fma(f2, f2, s);
                    double f3 = (double)x3 - (double)e4.w; s = fma(f3, f3, s);
                }
                if (s < bestd || (s == bestd && k < besti)) { bestd = s; besti = k; }
            }
#pragma unroll
            for (int off = 32; off; off >>= 1) {
                double od = __shfl_xor(bestd, off);
                int    oi = __shfl_xor(besti, off);
                if (od < bestd || (od == bestd && oi < besti)) { bestd = od; besti = oi; }
            }
            if (lane == 0) {
                idx_s[(w << 5) + r]  = besti;
                dist_s[(w << 5) + r] = (float)bestd;
            }
        }
    }
    __syncthreads();

    // ---- WG stats: strip flags, histogram, loss partial ----
    if (t < 512) {
        int k = idx_s[t] & 511;
        idx_s[t] = k;
        atomicAdd(&hist_s[k], 1);
        float v = dist_s[t];
#pragma unroll
        for (int off = 1; off < 64; off <<= 1) v += __shfl_xor(v, off);
        if (lane == 0) en_s[w] = v;           // en_s dead; reuse (w = 0..7)
    }
    __syncthreads();
    if (t < 512)
        __hip_atomic_store(&wsi[wg * WSTRIDE + t], hist_s[t],
                           __ATOMIC_RELAXED, __HIP_MEMORY_SCOPE_AGENT);
    if (t == 0) {
        float lsum = 0.f;
        for (int i = 0; i < 8; ++i) lsum += en_s[i];
        __hip_atomic_store(&wsi[wg * WSTRIDE + 512], __float_as_int(lsum),
                           __ATOMIC_RELAXED, __HIP_MEMORY_SCOPE_AGENT);
    }
    __syncthreads();
    if (t == 0)
        __hip_atomic_store(&wsi[wg * WSTRIDE + 513], MAGIC,
                           __ATOMIC_RELEASE, __HIP_MEMORY_SCOPE_AGENT);

    // ---- onehot phase A: wide zero-fill of this WG's 512 half-rows ----
    // half-row base global idx == 2 (mod 4) -> float2 + 127*float4 + float2
    {
        float4 z4 = {0.f, 0.f, 0.f, 0.f};
        float2 z2 = {0.f, 0.f};
        float* base_wg = oh + (((size_t)b0) << 19) + sphalf;
        for (int j = 0; j < 32; ++j) {
            int k = w + (j << 4);                       // wave w: chunks w,w+16,...
            float* cbase = base_wg + (((size_t)k) << 10);
            *(float4*)(cbase + 2 + (lane << 2)) = z4;   // f4 #0..63, 1KB contiguous
            if (lane < 63)
                *(float4*)(cbase + 2 + ((64 + lane) << 2)) = z4;  // f4 #64..126
            else {
                *(float2*)(cbase)       = z2;           // sp 0,1
                *(float2*)(cbase + 510) = z2;           // sp 510,511
            }
        }
    }
    __syncthreads();   // zero-fill complete before scatter (same-dword ordering)

    // ---- onehot phase B: scatter the 512 ones (targets L2-hot) ----
    if (t < 512) {
        int k = idx_s[t];
        oh[(((size_t)b0) << 19) + (((size_t)k) << 10) + sphalf + t] = 1.0f;
    }

    // ---- quant: float4 stores, gather hi+lo from LDS ----
    // half-row base global idx == 1 (mod 4) -> scalar + float2 + 127*float4 + scalar
    {
        float* qbase = qout + (((size_t)b0) << 16) + sphalf;
#pragma unroll
        for (int j = 0; j < 4; ++j) {
            int d = (w << 2) + j;                       // wave w: d rows 4w..4w+3
            const int ch = d >> 3, dj = d & 7;
            float* rb = qbase + (((size_t)d) << 10);
            // round A: lane -> f4 #lane (sp 3+4*lane); round B: f4 #(64+lane) | edges
#pragma unroll
            for (int rnd = 0; rnd < 2; ++rnd) {
                int m = (rnd << 6) + lane;
                if (m < 127) {
                    int s0 = 3 + (m << 2);
                    float vv[4];
#pragma unroll
                    for (int e = 0; e < 4; ++e) {
                        int k = idx_s[s0 + e];
                        int a = (k << 6) + (((ch ^ (k & 7)) << 3) + dj);
                        vv[e] = bf2f((unsigned short)Ehi[a]) + bf2f((unsigned short)Elo[a]);
                    }
                    float4 v4 = {vv[0], vv[1], vv[2], vv[3]};
                    *(float4*)(rb + s0) = v4;
                } else if (rnd == 1) {                  // lane 63: edges
                    int k0 = idx_s[0], k1 = idx_s[1], k2 = idx_s[2], k5 = idx_s[511];
                    int a0 = (k0 << 6) + (((ch ^ (k0 & 7)) << 3) + dj);
                    int a1 = (k1 << 6) + (((ch ^ (k1 & 7)) << 3) + dj);
                    int a2 = (k2 << 6) + (((ch ^ (k2 & 7)) << 3) + dj);
                    int a5 = (k5 << 6) + (((ch ^ (k5 & 7)) << 3) + dj);
                    rb[0] = bf2f((unsigned short)Ehi[a0]) + bf2f((unsigned short)Elo[a0]);
                    float2 e2 = { bf2f((unsigned short)Ehi[a1]) + bf2f((unsigned short)Elo[a1]),
                                  bf2f((unsigned short)Ehi[a2]) + bf2f((unsigned short)Elo[a2]) };
                    *(float2*)(rb + 1) = e2;
                    rb[511] = bf2f((unsigned short)Ehi[a5]) + bf2f((unsigned short)Elo[a5]);
                }
            }
        }
    }

    // ---- WG0: gather all stats, perplexity + loss ----
    if (wg == 0) {
        if (t < 256) {
            while (__hip_atomic_load(&wsi[t * WSTRIDE + 513],
                                     __ATOMIC_ACQUIRE, __HIP_MEMORY_SCOPE_AGENT) != MAGIC)
                __builtin_amdgcn_s_sleep(2);
        }
        __syncthreads();
        float plog = 0.f, lpart = 0.f;
        if (t < 512) {
            int s = 0;
            for (int wgi = 0; wgi < 256; ++wgi)
                s += __hip_atomic_load(&wsi[wgi * WSTRIDE + t],
                                       __ATOMIC_RELAXED, __HIP_MEMORY_SCOPE_AGENT);
            float p = (float)s * (1.f / (float)NTOT);
            plog = p * logf(p + 1e-10f);
        }
        if (t < 256)
            lpart = __int_as_float(__hip_atomic_load(&wsi[t * WSTRIDE + 512],
                                       __ATOMIC_RELAXED, __HIP_MEMORY_SCOPE_AGENT));
#pragma unroll
        for (int off = 1; off < 64; off <<= 1) {
            plog  += __shfl_xor(plog, off);
            lpart += __shfl_xor(lpart, off);
        }
        __syncthreads();
        if (lane == 0 && w < 8) en_s[w] = plog;
        if (lane == 0 && w < 4) dist_s[w] = lpart;
        __syncthreads();
        if (t == 0) {
            float ps = 0.f; for (int i = 0; i < 8; ++i) ps += en_s[i];
            float ls = 0.f; for (int i = 0; i < 4; ++i) ls += dist_s[i];
            out[OFF_PERP] = expf(-ps);
            out[OFF_LOSS] = 0.25f * ls / ((float)NTOT * 64.0f);
        }
    }
}

extern "C" void kernel_launch(void* const* d_in, const int* in_sizes, int n_in,
                              void* d_out, int out_size, void* d_ws, size_t ws_size,
                              hipStream_t stream) {
    const float* x  = (const float*)d_in[0];
    const float* cb = (const float*)d_in[1];
    vq_fused<<<256, 1024, 0, stream>>>(x, cb, (int*)d_ws, (float*)d_out);
}

// Round 7
// 413.157 us; speedup vs baseline: 1.3031x; 1.0109x over previous
//
#include <hip/hip_runtime.h>
#include <hip/hip_bf16.h>
#include <float.h>

// Problem: B=128, D=64, H=W=32, K=512. N = 131072 rows.
#define NTOT 131072

// d_out element offsets (fp32, concatenated in return order)
#define OFF_LOSS  0
#define OFF_QUANT 1
#define OFF_PERP  8388609
#define OFF_OH    8388610

#define FLAG_BIT (1 << 16)
#define TAU      1.5e-3f
#define MAGIC    0x5EEDF00D
#define WSTRIDE  516          // per-WG ints in ws: 512 hist + loss + flag + pad

typedef __attribute__((ext_vector_type(8))) short short8;
typedef __attribute__((ext_vector_type(4))) short short4v;
typedef __attribute__((ext_vector_type(4))) float f32x4;

__device__ inline unsigned short f2bf(float f) {
    unsigned u = __builtin_bit_cast(unsigned, f);
    unsigned r = (u + 0x7fffu + ((u >> 16) & 1u)) >> 16;   // RNE
    return (unsigned short)r;
}
__device__ inline float bf2f(unsigned short h) {
    return __builtin_bit_cast(float, ((unsigned)h) << 16);
}

// ONE persistent kernel, 256 WG x 1024 thr (1 WG/CU).
// WAVE SPECIALIZATION: waves 0-7 compute (64 rows each: X-frags -> MFMA
// argmin -> merge -> recheck), waves 8-15 stage the codebook into LDS and
// then zero-fill the WG's 1 MB onehot slice CONCURRENTLY with compute.
// After the join barrier: stats publish, scatter of ones, quant, WG0 tail.
__global__ __launch_bounds__(1024)
void vq_fused(const float* __restrict__ x, const float* __restrict__ cb,
              int* __restrict__ wsi, float* __restrict__ out) {
    __shared__ short Ehi[512 * 64];   // bf16 hi, XOR-swizzled 16B chunks
    __shared__ short Elo[512 * 64];   // bf16 lo
    __shared__ float en_s[512];
    __shared__ float dist_s[512];
    __shared__ int   idx_s[512];
    __shared__ int   hist_s[512];

    const int t = threadIdx.x, wg = blockIdx.x;
    const int w = t >> 6, lane = t & 63;
    const int c = lane & 15, g = lane >> 4;
    const int b0 = wg >> 1;
    const int sphalf = (wg & 1) << 9;
    float* qout = out + OFF_QUANT;
    float* oh   = out + OFF_OH;

    if (t < 512) hist_s[t] = 0;

    const float4* cb4 = (const float4*)cb;

    // X-frag registers (compute waves only use them)
    short8 bh[4][2], bl[4][2];
    float xnorm[4];

    if (w >= 8) {
        // ---- fill waves: stage codebook -> LDS bf16 hi/lo (swizzled) + enorm ----
        int j = w - 8;
#pragma unroll
        for (int i = 0; i < 16; ++i) {
            int e4 = (j << 6) + lane + (i << 9);     // 8192 float4 total, coalesced
            float4 v = cb4[e4];
            int k = e4 >> 4, q = e4 & 15;
            int base = (k << 6) + ((((q >> 1) ^ (k & 7)) << 3) + ((q & 1) << 2));
            float vv[4] = {v.x, v.y, v.z, v.w};
            short4v h4, l4;
#pragma unroll
            for (int e = 0; e < 4; ++e) {
                unsigned short h = f2bf(vv[e]);
                h4[e] = (short)h;
                l4[e] = (short)f2bf(vv[e] - bf2f(h));
            }
            *(short4v*)&Ehi[base] = h4;
            *(short4v*)&Elo[base] = l4;
        }
        // ||e||^2 (one code per thread of waves 8..15)
        {
            int i = t - 512;                          // 0..511
            const float4* r4 = cb4 + (i << 4);
            float s = 0.f;
#pragma unroll
            for (int jj = 0; jj < 16; ++jj) {
                float4 vv = r4[jj];
                s = fmaf(vv.x, vv.x, s); s = fmaf(vv.y, vv.y, s);
                s = fmaf(vv.z, vv.z, s); s = fmaf(vv.w, vv.w, s);
            }
            en_s[i] = s;
        }
    } else {
        // ---- compute waves: X B-frags + xnorm, registers only ----
        const float* xb = x + (((size_t)b0) << 16) + sphalf + (w << 6) + c;
#pragma unroll
        for (int xt = 0; xt < 4; ++xt) {
            float xn2 = 0.f;
#pragma unroll
            for (int ks = 0; ks < 2; ++ks) {
                short8 h8, l8;
#pragma unroll
                for (int e = 0; e < 8; ++e) {
                    float xv = xb[(xt << 4) + ((size_t)((ks << 5) + (g << 3) + e) << 10)];
                    unsigned short hh = f2bf(xv);
                    h8[e] = (short)hh;
                    l8[e] = (short)f2bf(xv - bf2f(hh));
                    xn2 = fmaf(xv, xv, xn2);
                }
                bh[xt][ks] = h8; bl[xt][ks] = l8;
            }
            xn2 += __shfl_xor(xn2, 16);
            xn2 += __shfl_xor(xn2, 32);
            xnorm[xt] = xn2;
        }
    }
    __syncthreads();      // stage + X done

    if (w < 8) {
        // ---- MFMA argmin over 32 k-tiles (4 x-tiles per wave) ----
        float v1[4] = {FLT_MAX, FLT_MAX, FLT_MAX, FLT_MAX};
        float v2[4] = {FLT_MAX, FLT_MAX, FLT_MAX, FLT_MAX};
        int   i1[4] = {0, 0, 0, 0}, i2v[4] = {0, 0, 0, 0};
        const int sw = c & 7;
        const short* ph = &Ehi[c << 6];
        const short* pl = &Elo[c << 6];
        for (int kt = 0; kt < 32; ++kt) {
            const short* rh = ph + (kt << 10);
            const short* rl = pl + (kt << 10);
            short8 ah0 = *(const short8*)(rh + ((g ^ sw) << 3));
            short8 ah1 = *(const short8*)(rh + (((g + 4) ^ sw) << 3));
            short8 al0 = *(const short8*)(rl + ((g ^ sw) << 3));
            short8 al1 = *(const short8*)(rl + (((g + 4) ^ sw) << 3));
            float4 en4 = *(const float4*)&en_s[(kt << 4) + (g << 2)];
            float en_[4] = {en4.x, en4.y, en4.z, en4.w};
#pragma unroll
            for (int xt = 0; xt < 4; ++xt) {
                f32x4 acc = {0.f, 0.f, 0.f, 0.f};
                acc = __builtin_amdgcn_mfma_f32_16x16x32_bf16(ah0, bh[xt][0], acc, 0, 0, 0);
                acc = __builtin_amdgcn_mfma_f32_16x16x32_bf16(ah1, bh[xt][1], acc, 0, 0, 0);
                acc = __builtin_amdgcn_mfma_f32_16x16x32_bf16(al0, bh[xt][0], acc, 0, 0, 0);
                acc = __builtin_amdgcn_mfma_f32_16x16x32_bf16(al1, bh[xt][1], acc, 0, 0, 0);
                acc = __builtin_amdgcn_mfma_f32_16x16x32_bf16(ah0, bl[xt][0], acc, 0, 0, 0);
                acc = __builtin_amdgcn_mfma_f32_16x16x32_bf16(ah1, bl[xt][1], acc, 0, 0, 0);
#pragma unroll
                for (int r = 0; r < 4; ++r) {
                    float dd = fmaf(-2.0f, acc[r], en_[r]);
                    int k = (kt << 4) + (g << 2) + r;
                    bool lt1 = dd < v1[xt];
                    bool lt2 = dd < v2[xt];
                    v2[xt] = lt1 ? v1[xt] : (lt2 ? dd : v2[xt]);
                    i2v[xt] = lt1 ? i1[xt] : (lt2 ? k : i2v[xt]);
                    v1[xt] = lt1 ? dd : v1[xt];
                    i1[xt] = lt1 ? k : i1[xt];
                }
            }
        }

        // ---- cross-lane merge (lanes c,c+16,c+32,c+48 hold disjoint k-classes) ----
#pragma unroll
        for (int xt = 0; xt < 4; ++xt) {
            float V1 = v1[xt], V2 = v2[xt]; int I1 = i1[xt], I2 = i2v[xt];
#pragma unroll
            for (int off = 16; off <= 32; off <<= 1) {
                float o1 = __shfl_xor(V1, off); int oi1 = __shfl_xor(I1, off);
                float o2 = __shfl_xor(V2, off); int oi2 = __shfl_xor(I2, off);
                if (o1 < V1 || (o1 == V1 && oi1 < I1)) {
                    V2 = V1; I2 = I1; V1 = o1; I1 = oi1;
                } else if (o1 < V2 || (o1 == V2 && oi1 < I2)) { V2 = o1; I2 = oi1; }
                if (o2 < V2 || (o2 == V2 && oi2 < I2)) { V2 = o2; I2 = oi2; }
            }
            if (g == 0) {
                int r = (w << 6) + (xt << 4) + c;
                idx_s[r]  = I1 | ((V2 - V1 < TAU) ? FLAG_BIT : 0);
                dist_s[r] = xnorm[xt] + V1;
            }
        }

        // ---- wave-local fp64 recheck of near-ties (2 halves of 32 rows) ----
        for (int half = 0; half < 2; ++half) {
            int rbase = (w << 6) + (half << 5);
            int rowfull = (lane < 32) ? idx_s[rbase + lane] : 0;
            unsigned long long m = __ballot((lane < 32) && (rowfull & FLAG_BIT));
            while (m) {
                int r = __ffsll((long long)m) - 1; m &= m - 1;
                int sp = sphalf + rbase + r;
                float xd = x[(((size_t)b0) << 16) + (((size_t)lane) << 10) + sp]; // lane=d
                double bestd = 1e300; int besti = 0x7fffffff;
                for (int kk = 0; kk < 8; ++kk) {
                    int k = (lane << 3) + kk;
                    double s = 0.0;
#pragma unroll
                    for (int d4 = 0; d4 < 16; ++d4) {
                        float4 e4 = cb4[(k << 4) + d4];
                        float x0 = __shfl(xd, d4 * 4 + 0);
                        float x1 = __shfl(xd, d4 * 4 + 1);
                        float x2 = __shfl(xd, d4 * 4 + 2);
                        float x3 = __shfl(xd, d4 * 4 + 3);
                        double f0 = (double)x0 - (double)e4.x; s = fma(f0, f0, s);
                        double f1 = (double)x1 - (double)e4.y; s = fma(f1, f1, s);
                        double f2 = (double)x2 - (double)e4.z; s = fma(f2, f2, s);
                        double f3 = (double)x3 - (double)e4.w; s = fma(f3, f3, s);
                    }
                    if (s < bestd || (s == bestd && k < besti)) { bestd = s; besti = k; }
                }
#pragma unroll
                for (int off = 32; off; off >>= 1) {
                    double od = __shfl_xor(bestd, off);
                    int    oi = __shfl_xor(besti, off);
                    if (od < bestd || (od == bestd && oi < besti)) { bestd = od; besti = oi; }
                }
                if (lane == 0) {
                    idx_s[rbase + r]  = besti;
                    dist_s[rbase + r] = (float)bestd;
                }
            }
        }
    } else {
        // ---- fill waves: zero the WG's 1 MB onehot slice (concurrent w/ compute) ----
        int j = w - 8;
        float4 z4 = {0.f, 0.f, 0.f, 0.f};
        float2 z2 = {0.f, 0.f};
        float* base_wg = oh + (((size_t)b0) << 19) + sphalf;
        for (int it = 0; it < 64; ++it) {
            int k = j + (it << 3);                    // chunks j, j+8, ..., j+504
            float* cbase = base_wg + (((size_t)k) << 10);
            *(float4*)(cbase + 2 + (lane << 2)) = z4;         // sp 2..257
            if (lane < 63)
                *(float4*)(cbase + 2 + ((64 + lane) << 2)) = z4;  // sp 258..509
            else {
                *(float2*)(cbase)       = z2;         // sp 0,1
                *(float2*)(cbase + 510) = z2;         // sp 510,511
            }
        }
    }
    __syncthreads();   // compute done AND zeros drained (syncthreads waits vmcnt)

    // ---- WG stats: strip flags, histogram, loss partial ----
    if (t < 512) {
        int k = idx_s[t] & 511;
        idx_s[t] = k;
        atomicAdd(&hist_s[k], 1);
        float v = dist_s[t];
#pragma unroll
        for (int off = 1; off < 64; off <<= 1) v += __shfl_xor(v, off);
        if (lane == 0) en_s[w] = v;           // en_s dead; reuse (w = 0..7)
    }
    __syncthreads();
    if (t < 512)
        __hip_atomic_store(&wsi[wg * WSTRIDE + t], hist_s[t],
                           __ATOMIC_RELAXED, __HIP_MEMORY_SCOPE_AGENT);
    if (t == 0) {
        float lsum = 0.f;
        for (int i = 0; i < 8; ++i) lsum += en_s[i];
        __hip_atomic_store(&wsi[wg * WSTRIDE + 512], __float_as_int(lsum),
                           __ATOMIC_RELAXED, __HIP_MEMORY_SCOPE_AGENT);
    }
    __syncthreads();
    if (t == 0)
        __hip_atomic_store(&wsi[wg * WSTRIDE + 513], MAGIC,
                           __ATOMIC_RELEASE, __HIP_MEMORY_SCOPE_AGENT);

    // ---- scatter the 512 ones (targets L2-hot, zeroed by this WG) ----
    if (t < 512) {
        int k = idx_s[t];
        oh[(((size_t)b0) << 19) + (((size_t)k) << 10) + sphalf + t] = 1.0f;
    }

    // ---- quant: float4 stores, gather hi+lo from LDS ----
    // half-row base global idx == 1 (mod 4) -> scalar + float2 + 127*float4 + scalar
    {
        float* qbase = qout + (((size_t)b0) << 16) + sphalf;
#pragma unroll
        for (int j = 0; j < 4; ++j) {
            int d = (w << 2) + j;                       // wave w: d rows 4w..4w+3
            const int ch = d >> 3, dj = d & 7;
            float* rb = qbase + (((size_t)d) << 10);
#pragma unroll
            for (int rnd = 0; rnd < 2; ++rnd) {
                int m = (rnd << 6) + lane;
                if (m < 127) {
                    int s0 = 3 + (m << 2);
                    float vv[4];
#pragma unroll
                    for (int e = 0; e < 4; ++e) {
                        int k = idx_s[s0 + e];
                        int a = (k << 6) + (((ch ^ (k & 7)) << 3) + dj);
                        vv[e] = bf2f((unsigned short)Ehi[a]) + bf2f((unsigned short)Elo[a]);
                    }
                    float4 v4 = {vv[0], vv[1], vv[2], vv[3]};
                    *(float4*)(rb + s0) = v4;
                } else if (rnd == 1) {                  // lane 63: edges
                    int k0 = idx_s[0], k1 = idx_s[1], k2 = idx_s[2], k5 = idx_s[511];
                    int a0 = (k0 << 6) + (((ch ^ (k0 & 7)) << 3) + dj);
                    int a1 = (k1 << 6) + (((ch ^ (k1 & 7)) << 3) + dj);
                    int a2 = (k2 << 6) + (((ch ^ (k2 & 7)) << 3) + dj);
                    int a5 = (k5 << 6) + (((ch ^ (k5 & 7)) << 3) + dj);
                    rb[0] = bf2f((unsigned short)Ehi[a0]) + bf2f((unsigned short)Elo[a0]);
                    float2 e2 = { bf2f((unsigned short)Ehi[a1]) + bf2f((unsigned short)Elo[a1]),
                                  bf2f((unsigned short)Ehi[a2]) + bf2f((unsigned short)Elo[a2]) };
                    *(float2*)(rb + 1) = e2;
                    rb[511] = bf2f((unsigned short)Ehi[a5]) + bf2f((unsigned short)Elo[a5]);
                }
            }
        }
    }

    // ---- WG0: gather all stats, perplexity + loss ----
    if (wg == 0) {
        if (t < 256) {
            while (__hip_atomic_load(&wsi[t * WSTRIDE + 513],
                                     __ATOMIC_ACQUIRE, __HIP_MEMORY_SCOPE_AGENT) != MAGIC)
                __builtin_amdgcn_s_sleep(2);
        }
        __syncthreads();
        float plog = 0.f, lpart = 0.f;
        if (t < 512) {
            int s = 0;
            for (int wgi = 0; wgi < 256; ++wgi)
                s += __hip_atomic_load(&wsi[wgi * WSTRIDE + t],
                                       __ATOMIC_RELAXED, __HIP_MEMORY_SCOPE_AGENT);
            float p = (float)s * (1.f / (float)NTOT);
            plog = p * logf(p + 1e-10f);
        }
        if (t < 256)
            lpart = __int_as_float(__hip_atomic_load(&wsi[t * WSTRIDE + 512],
                                       __ATOMIC_RELAXED, __HIP_MEMORY_SCOPE_AGENT));
#pragma unroll
        for (int off = 1; off < 64; off <<= 1) {
            plog  += __shfl_xor(plog, off);
            lpart += __shfl_xor(lpart, off);
        }
        __syncthreads();
        if (lane == 0 && w < 8) en_s[w] = plog;
        if (lane == 0 && w < 4) dist_s[w] = lpart;
        __syncthreads();
        if (t == 0) {
            float ps = 0.f; for (int i = 0; i < 8; ++i) ps += en_s[i];
            float ls = 0.f; for (int i = 0; i < 4; ++i) ls += dist_s[i];
            out[OFF_PERP] = expf(-ps);
            out[OFF_LOSS] = 0.25f * ls / ((float)NTOT * 64.0f);
        }
    }
}

extern "C" void kernel_launch(void* const* d_in, const int* in_sizes, int n_in,
                              void* d_out, int out_size, void* d_ws, size_t ws_size,
                              hipStream_t stream) {
    const float* x  = (const float*)d_in[0];
    const float* cb = (const float*)d_in[1];
    vq_fused<<<256, 1024, 0, stream>>>(x, cb, (int*)d_ws, (float*)d_out);
}